// Round 1
// baseline (436.700 us; speedup 1.0000x reference)
//
#include <hip/hip_runtime.h>
#include <hip/hip_bf16.h>
#include <float.h>

#define NEG 0.2f
#define SEGSHIFT 13   // src-range segments of 8192 nodes

__device__ __forceinline__ float leaky(float x) { return x > 0.0f ? x : NEG * x; }

__device__ __forceinline__ unsigned short f2bf(float f) {
  unsigned x = __float_as_uint(f);
  unsigned r = (x + 0x7fffu + ((x >> 16) & 1u)) >> 16;  // round-to-nearest-even
  return (unsigned short)r;
}

__device__ __forceinline__ float2 bf2f2(unsigned u) {   // u = (ch1<<16)|ch0
  float2 r;
  r.x = __uint_as_float(u << 16);
  r.y = __uint_as_float(u & 0xffff0000u);
  return r;
}

using frag8 = __attribute__((ext_vector_type(8))) short;   // 8 bf16
using f32x4v = __attribute__((ext_vector_type(4))) float;  // 4 fp32 acc

// ---------------------------------------------------------------- utilities
__global__ void zero_kernel(int* __restrict__ p, int n) {
  int i = blockIdx.x * blockDim.x + threadIdx.x;
  int stride = gridDim.x * blockDim.x;
  for (; i < n; i += stride) p[i] = 0;
}

// W [K][128] fp32 -> Wt [128][K] bf16 (transposed, k-contiguous)
__global__ void wcvt_kernel(const float* __restrict__ W, unsigned short* __restrict__ Wt, int K) {
  int i = blockIdx.x * 256 + threadIdx.x;
  if (i >= K * 128) return;
  int k = i >> 7, n = i & 127;
  Wt[n * K + k] = f2bf(W[i]);
}

// count per (dst, src-segment) bucket
__global__ void count_kernel(const int* __restrict__ ei, int* __restrict__ degseg,
                             int E, int N, int nseg) {
  int i = blockIdx.x * blockDim.x + threadIdx.x;
  if (i >= E + N) return;
  int src, dst;
  if (i < E) { src = ei[i]; dst = ei[E + i]; } else { src = dst = i - E; }
  atomicAdd(&degseg[(size_t)dst * nseg + (src >> SEGSHIFT)], 1);
}

__global__ __launch_bounds__(1024) void scan_block_kernel(const int* __restrict__ deg,
                                                          int* __restrict__ row_start,
                                                          int* __restrict__ sums, int n) {
  __shared__ int buf[1024];
  int t = threadIdx.x;
  int idx = blockIdx.x * 1024 + t;
  int x = (idx < n) ? deg[idx] : 0;
  int v = x;
  buf[t] = v;
  __syncthreads();
  for (int off = 1; off < 1024; off <<= 1) {
    int a = (t >= off) ? buf[t - off] : 0;
    __syncthreads();
    v += a;
    buf[t] = v;
    __syncthreads();
  }
  if (idx < n) row_start[idx] = v - x;  // local exclusive
  if (t == 1023) sums[blockIdx.x] = v;  // chunk total
}

__global__ __launch_bounds__(1024) void scan_sums_kernel(int* __restrict__ sums,
                                                         int* __restrict__ row_start,
                                                         int nch, int n) {
  __shared__ int buf[1024];
  int t = threadIdx.x;
  int x = (t < nch) ? sums[t] : 0;
  int v = x;
  buf[t] = v;
  __syncthreads();
  for (int off = 1; off < 1024; off <<= 1) {
    int a = (t >= off) ? buf[t - off] : 0;
    __syncthreads();
    v += a;
    buf[t] = v;
    __syncthreads();
  }
  if (t < nch) sums[t] = v - x;        // exclusive chunk offsets
  if (t == 1023) row_start[n] = v;     // grand total
}

__global__ __launch_bounds__(1024) void scan_add_kernel(int* __restrict__ row_start,
                                                        const int* __restrict__ sums, int n) {
  int idx = blockIdx.x * 1024 + threadIdx.x;
  if (idx < n) row_start[idx] += sums[blockIdx.x];
}

// single-pass fill into (dst, src-segment) buckets (dst is implicit in agg now)
__global__ void fill_kernel(const int* __restrict__ ei, int* __restrict__ cursor,
                            const int* __restrict__ rowseg, int* __restrict__ csr_src,
                            int E, int N, int nseg) {
  int i = blockIdx.x * blockDim.x + threadIdx.x;
  if (i >= E + N) return;
  int src, dst;
  if (i < E) { src = ei[i]; dst = ei[E + i]; } else { src = dst = i - E; }
  size_t b = (size_t)dst * nseg + (src >> SEGSHIFT);
  int pos = atomicAdd(&cursor[b], 1);
  csr_src[rowseg[b] + pos] = src;
}

// ---------------------------------------------------------------- MFMA GEMM  Hb = bf16(X @ W), fused alpha dots
// Wt: bf16 [128][K] pre-transposed. FP32IN: stage-converts fp32 input rows.
template <int FP32IN>
__global__ __launch_bounds__(256) void gemm_kernel(const void* __restrict__ Xin,
                                                   const unsigned short* __restrict__ Wtg,
                                                   unsigned short* __restrict__ Hb,
                                                   const float* __restrict__ a_src,
                                                   const float* __restrict__ a_dst,
                                                   float* __restrict__ as_arr,
                                                   float* __restrict__ ad_arr,
                                                   int nrows, int K) {
  __shared__ unsigned short Wt[128][136];  // [n][k] bf16
  __shared__ unsigned short Xs[64][136];   // [row][k] bf16; reused for C transpose
  int t = threadIdx.x;
  int wave = t >> 6, lane = t & 63;
  int n0 = lane & 15, quad = lane >> 4;
  int row0 = blockIdx.x * 64, wrow = wave * 16;

  // stage Wt from pre-converted bf16 (16B chunks)
  for (int idx = t; idx < (K * 128) / 8; idx += 256) {
    int n = idx / (K >> 3), c8 = idx % (K >> 3);
    *(uint4*)(&Wt[n][c8 * 8]) = *(const uint4*)(Wtg + (size_t)n * K + c8 * 8);
  }
  int rowElems = K >> 3;
  if (FP32IN) {
    const float* Xf = (const float*)Xin;
    for (int idx = t; idx < 64 * K; idx += 256) {
      int r = idx / K, k = idx % K;
      int gr = row0 + r;
      Xs[r][k] = f2bf(gr < nrows ? Xf[(size_t)gr * K + k] : 0.f);
    }
  } else {
    const unsigned short* Xb = (const unsigned short*)Xin;
    for (int idx = t; idx < 64 * rowElems; idx += 256) {
      int r = idx / rowElems, c8 = idx % rowElems;
      int gr = row0 + r;
      uint4 v = make_uint4(0, 0, 0, 0);
      if (gr < nrows) v = *(const uint4*)(Xb + (size_t)gr * K + c8 * 8);
      *(uint4*)(&Xs[r][c8 * 8]) = v;
    }
  }
  __syncthreads();

  f32x4v acc[8];
#pragma unroll
  for (int c = 0; c < 8; ++c) acc[c] = (f32x4v){0.f, 0.f, 0.f, 0.f};

  for (int kb = 0; kb < K; kb += 32) {
    frag8 a = *(const frag8*)(&Xs[wrow + n0][kb + quad * 8]);
#pragma unroll
    for (int c = 0; c < 8; ++c) {
      frag8 b = *(const frag8*)(&Wt[c * 16 + n0][kb + quad * 8]);
      acc[c] = __builtin_amdgcn_mfma_f32_16x16x32_bf16(a, b, acc[c], 0, 0, 0);
    }
  }

  float asv[8], adv[8];
#pragma unroll
  for (int c = 0; c < 8; ++c) {
    asv[c] = a_src[c * 16 + n0];
    adv[c] = a_dst[c * 16 + n0];
  }
#pragma unroll
  for (int r = 0; r < 4; ++r) {
    float ps[4] = {0.f, 0.f, 0.f, 0.f}, pd[4] = {0.f, 0.f, 0.f, 0.f};
#pragma unroll
    for (int c = 0; c < 8; ++c) {
      int h = c >> 1;
      ps[h] += acc[c][r] * asv[c];
      pd[h] += acc[c][r] * adv[c];
    }
#pragma unroll
    for (int off = 1; off < 16; off <<= 1) {
#pragma unroll
      for (int h = 0; h < 4; ++h) {
        ps[h] += __shfl_xor(ps[h], off);
        pd[h] += __shfl_xor(pd[h], off);
      }
    }
    if (n0 == 0) {
      int m = row0 + wrow + quad * 4 + r;
      if (m < nrows) {
#pragma unroll
        for (int h = 0; h < 4; ++h) {
          as_arr[(size_t)m * 4 + h] = ps[h];
          ad_arr[(size_t)m * 4 + h] = pd[h];
        }
      }
    }
  }

  __syncthreads();
#pragma unroll
  for (int c = 0; c < 8; ++c)
#pragma unroll
    for (int r = 0; r < 4; ++r)
      Xs[wrow + quad * 4 + r][c * 16 + n0] = f2bf(acc[c][r]);
  __syncthreads();
  for (int idx = t; idx < 64 * 16; idx += 256) {
    int r = idx >> 4, c8 = idx & 15;
    int gr = row0 + r;
    if (gr < nrows)
      *(uint4*)(Hb + (size_t)gr * 128 + c8 * 8) = *(const uint4*)(&Xs[r][c8 * 8]);
  }
}

// ---------------------------------------------------------------- aggregation
// Fused e-computation (exp(leaky(as[s]+ad[n]))) — no earr, no csr_dst.
// Quad-edge layout: 16-lane subgroups each own one edge of a 4-edge packet;
// each lane covers 8 channels (uint4 = 4x packed bf16 pairs). Unroll-2 ->
// 8 row-gathers in flight per wave (vs 4 before). Cross-subgroup combine via
// shfl_xor(16)+shfl_xor(32) at the end.
template <int POOL>
__global__ __launch_bounds__(256) void agg_kernel(const unsigned short* __restrict__ Hb,
                                                  const float* __restrict__ as_arr,
                                                  const float* __restrict__ ad_arr,
                                                  const int* __restrict__ csr_src,
                                                  const int* __restrict__ rowseg,
                                                  const float* __restrict__ bias,
                                                  unsigned short* __restrict__ xnext,
                                                  const int* __restrict__ batch,
                                                  float* __restrict__ pooled,
                                                  int N, int nseg) {
  int wid = threadIdx.x >> 6;
  int lane = threadIdx.x & 63;
  int n = blockIdx.x * 4 + wid;
  if (n >= N) return;
  int rs = rowseg[(size_t)n * nseg];
  int re = rowseg[(size_t)n * nseg + nseg];
  int l16 = lane & 15;   // channel-block within the row (8 channels each)
  int sub = lane >> 4;   // which edge of the 4-edge packet
  int head = l16 >> 2;   // 32 channels per head, 8 per lane

  float adv = ad_arr[(size_t)n * 4 + head];
  const uint4* hb4 = (const uint4*)Hb;  // row = 16 uint4

  float denom = 0.f;
  float acc[8];
#pragma unroll
  for (int c = 0; c < 8; ++c) acc[c] = 0.f;

  int i = rs;
  for (; i + 8 <= re; i += 8) {
    int s0 = csr_src[i + sub];
    int s1 = csr_src[i + 4 + sub];
    float as0 = as_arr[(size_t)s0 * 4 + head];
    float as1 = as_arr[(size_t)s1 * 4 + head];
    uint4 u0 = hb4[(size_t)s0 * 16 + l16];
    uint4 u1 = hb4[(size_t)s1 * 16 + l16];
    float e0 = __expf(fminf(leaky(as0 + adv), 80.f));
    float e1 = __expf(fminf(leaky(as1 + adv), 80.f));
    denom += e0 + e1;
    float2 f;
    f = bf2f2(u0.x); acc[0] += e0 * f.x; acc[1] += e0 * f.y;
    f = bf2f2(u0.y); acc[2] += e0 * f.x; acc[3] += e0 * f.y;
    f = bf2f2(u0.z); acc[4] += e0 * f.x; acc[5] += e0 * f.y;
    f = bf2f2(u0.w); acc[6] += e0 * f.x; acc[7] += e0 * f.y;
    f = bf2f2(u1.x); acc[0] += e1 * f.x; acc[1] += e1 * f.y;
    f = bf2f2(u1.y); acc[2] += e1 * f.x; acc[3] += e1 * f.y;
    f = bf2f2(u1.z); acc[4] += e1 * f.x; acc[5] += e1 * f.y;
    f = bf2f2(u1.w); acc[6] += e1 * f.x; acc[7] += e1 * f.y;
  }
  for (; i < re; i += 4) {
    if (i + sub < re) {
      int s0 = csr_src[i + sub];
      float as0 = as_arr[(size_t)s0 * 4 + head];
      uint4 u0 = hb4[(size_t)s0 * 16 + l16];
      float e0 = __expf(fminf(leaky(as0 + adv), 80.f));
      denom += e0;
      float2 f;
      f = bf2f2(u0.x); acc[0] += e0 * f.x; acc[1] += e0 * f.y;
      f = bf2f2(u0.y); acc[2] += e0 * f.x; acc[3] += e0 * f.y;
      f = bf2f2(u0.z); acc[4] += e0 * f.x; acc[5] += e0 * f.y;
      f = bf2f2(u0.w); acc[6] += e0 * f.x; acc[7] += e0 * f.y;
    }
  }

  // combine the 4 subgroup partials (lanes L, L^16, L^32, L^48 share channels)
  denom += __shfl_xor(denom, 16);
#pragma unroll
  for (int c = 0; c < 8; ++c) acc[c] += __shfl_xor(acc[c], 16);
  denom += __shfl_xor(denom, 32);
#pragma unroll
  for (int c = 0; c < 8; ++c) acc[c] += __shfl_xor(acc[c], 32);

  float inv = 1.0f / (denom + 1e-16f);
  if (POOL) {
    int g = batch[n];
    int c0 = 2 * sub;  // each lane commits 2 of its 8 channels -> 128 unique
    float v0 = leaky(acc[c0] * inv + bias[8 * l16 + c0]);
    float v1 = leaky(acc[c0 + 1] * inv + bias[8 * l16 + c0 + 1]);
    atomicAdd(&pooled[(size_t)g * 128 + 8 * l16 + c0], v0);
    atomicAdd(&pooled[(size_t)g * 128 + 8 * l16 + c0 + 1], v1);
  } else {
    if (sub == 0) {
      float4 bv0 = *(const float4*)(bias + 8 * l16);
      float4 bv1 = *(const float4*)(bias + 8 * l16 + 4);
      float v0 = leaky(acc[0] * inv + bv0.x);
      float v1 = leaky(acc[1] * inv + bv0.y);
      float v2 = leaky(acc[2] * inv + bv0.z);
      float v3 = leaky(acc[3] * inv + bv0.w);
      float v4 = leaky(acc[4] * inv + bv1.x);
      float v5 = leaky(acc[5] * inv + bv1.y);
      float v6 = leaky(acc[6] * inv + bv1.z);
      float v7 = leaky(acc[7] * inv + bv1.w);
      uint4 pk;
      pk.x = ((unsigned)f2bf(v1) << 16) | (unsigned)f2bf(v0);
      pk.y = ((unsigned)f2bf(v3) << 16) | (unsigned)f2bf(v2);
      pk.z = ((unsigned)f2bf(v5) << 16) | (unsigned)f2bf(v4);
      pk.w = ((unsigned)f2bf(v7) << 16) | (unsigned)f2bf(v6);
      ((uint4*)xnext)[(size_t)n * 16 + l16] = pk;
    }
  }
}

// ---------------------------------------------------------------- head
__global__ void head_kernel(const float* __restrict__ pooled, const float* __restrict__ fc_w,
                            const float* __restrict__ fc_b, const float* __restrict__ bn_g,
                            const float* __restrict__ bn_b, float* __restrict__ out, int G) {
  int t = threadIdx.x;
  int g = blockIdx.x * 8 + (t >> 5);
  int j = t & 31;
  if (g >= G) return;
  const float* pr = pooled + (size_t)g * 128;
  float acc = 0.f;
#pragma unroll 8
  for (int k = 0; k < 128; ++k) acc += pr[k] * fc_w[k * 32 + j];
  const float inv = 0.9999950000374997f;  // 1/sqrt(1+1e-5)
  out[g * 32 + j] = bn_g[j] * (acc + fc_b[j]) * inv + bn_b[j];
}

// ---------------------------------------------------------------- launch
extern "C" void kernel_launch(void* const* d_in, const int* in_sizes, int n_in,
                              void* d_out, int out_size, void* d_ws, size_t ws_size,
                              hipStream_t stream) {
  const float* x = (const float*)d_in[0];
  const int* ei = (const int*)d_in[1];
  const int* batch = (const int*)d_in[2];
  const float* Wm[3] = {(const float*)d_in[3], (const float*)d_in[7], (const float*)d_in[11]};
  const float* a_s[3] = {(const float*)d_in[4], (const float*)d_in[8], (const float*)d_in[12]};
  const float* a_d[3] = {(const float*)d_in[5], (const float*)d_in[9], (const float*)d_in[13]};
  const float* bb[3] = {(const float*)d_in[6], (const float*)d_in[10], (const float*)d_in[14]};
  const float* fc_w = (const float*)d_in[15];
  const float* fc_b = (const float*)d_in[16];
  const float* bn_g = (const float*)d_in[17];
  const float* bn_b = (const float*)d_in[18];
  float* out = (float*)d_out;

  int N = in_sizes[0] / 64;
  int E = in_sizes[1] / 2;
  int G = out_size / 32;
  int Etot = E + N;
  int nseg = ((N - 1) >> SEGSHIFT) + 1;
  int L = N * nseg;   // bucket count

  char* p = (char*)d_ws;
  auto carve = [&](size_t bytes) {
    char* r = p;
    p += (bytes + 255) & ~size_t(255);
    return r;
  };
  int* degseg    = (int*)carve((size_t)L * 4);
  int* cursor    = (int*)carve((size_t)L * 4);
  float* pooled  = (float*)carve((size_t)G * 128 * 4);
  int* rowseg    = (int*)carve((size_t)(L + 1) * 4);
  int* sums      = (int*)carve(4096);
  int* csr_src   = (int*)carve((size_t)Etot * 4);
  unsigned short* Hb  = (unsigned short*)carve((size_t)N * 128 * 2);     // bf16 features
  unsigned short* Xb  = (unsigned short*)carve((size_t)N * 128 * 2);     // bf16 layer input
  unsigned short* Wt0 = (unsigned short*)carve(64 * 128 * 2);            // bf16 W^T per layer
  unsigned short* Wt1 = (unsigned short*)carve(128 * 128 * 2);
  unsigned short* Wt2 = (unsigned short*)carve(128 * 128 * 2);
  float* as_arr  = (float*)carve((size_t)N * 4 * 4);
  float* ad_arr  = (float*)carve((size_t)N * 4 * 4);

  // zero degseg+cursor+pooled (contiguous carve region, pads included)
  int nz = (int)(((char*)(pooled + (size_t)G * 128) - (char*)degseg) / 4);
  zero_kernel<<<512, 256, 0, stream>>>(degseg, nz);

  // pre-transpose/convert weights
  wcvt_kernel<<<(64 * 128 + 255) / 256, 256, 0, stream>>>(Wm[0], Wt0, 64);
  wcvt_kernel<<<(128 * 128 + 255) / 256, 256, 0, stream>>>(Wm[1], Wt1, 128);
  wcvt_kernel<<<(128 * 128 + 255) / 256, 256, 0, stream>>>(Wm[2], Wt2, 128);

  // CSR build: per-(dst, src-seg) buckets, single fill pass
  int egrid = (Etot + 255) / 256;
  count_kernel<<<egrid, 256, 0, stream>>>(ei, degseg, E, N, nseg);
  int nch = (L + 1023) / 1024;
  scan_block_kernel<<<nch, 1024, 0, stream>>>(degseg, rowseg, sums, L);
  scan_sums_kernel<<<1, 1024, 0, stream>>>(sums, rowseg, nch, L);
  scan_add_kernel<<<nch, 1024, 0, stream>>>(rowseg, sums, L);
  fill_kernel<<<egrid, 256, 0, stream>>>(ei, cursor, rowseg, csr_src, E, N, nseg);

  int ggrid = (N + 63) / 64;
  int ngrid = (N + 3) / 4;

  // layer 0 (K=64, fp32 input direct)
  gemm_kernel<1><<<ggrid, 256, 0, stream>>>(x, Wt0, Hb, a_s[0], a_d[0], as_arr, ad_arr, N, 64);
  agg_kernel<0><<<ngrid, 256, 0, stream>>>(Hb, as_arr, ad_arr, csr_src, rowseg, bb[0],
                                           Xb, nullptr, nullptr, N, nseg);
  // layer 1 (K=128)
  gemm_kernel<0><<<ggrid, 256, 0, stream>>>(Xb, Wt1, Hb, a_s[1], a_d[1], as_arr, ad_arr, N, 128);
  agg_kernel<0><<<ngrid, 256, 0, stream>>>(Hb, as_arr, ad_arr, csr_src, rowseg, bb[1],
                                           Xb, nullptr, nullptr, N, nseg);
  // layer 2 (K=128), fused pooling
  gemm_kernel<0><<<ggrid, 256, 0, stream>>>(Xb, Wt2, Hb, a_s[2], a_d[2], as_arr, ad_arr, N, 128);
  agg_kernel<1><<<ngrid, 256, 0, stream>>>(Hb, as_arr, ad_arr, csr_src, rowseg, bb[2],
                                           nullptr, batch, pooled, N, nseg);

  head_kernel<<<(G + 7) / 8, 256, 0, stream>>>(pooled, fc_w, fc_b, bn_g, bn_b, out, G);
}